// Round 1
// 10219.643 us; speedup vs baseline: 1.2466x; 1.2466x over previous
//
#include <hip/hip_runtime.h>
#include <math.h>

// Backprop_29188597744223 — 1024-step sequential MLP training scan.
//
//   k_gram : G = X·Xᵀ (lower triangle + diag tiles), grid-parallel
//   k_z10  : Z10 = X·W1_init, grid-parallel
//   k2_seq : ONE workgroup, 512 threads (8 waves). Thread (p,q) owns a 16x8
//            tile of W2 (R2, lazy-scaled: W2_phys = s2·R2) and a 16x2 tile
//            of W3 (lazy-scaled s3) as named SSA registers. Per step: 10
//            barrier-fenced phases; the W2/W3 rank-1 update is DEFERRED and
//            fused into the next step's A phase (overlaps A's LDS latency);
//            scalar norm recurrences (incl. f64 n1) run on wave 0 only and
//            broadcast 8 scalars via LDS; biases stored pre-norm with rb
//            folded at use; NO global stores inside the step loop (o1/c
//            flushed once per 64-step block from zo/ch).
//   k_w1out: W1_final = s1_f·(W1_init + Xᵀ·diag(c)·O1), grid-parallel

#define LRC  0.01f
#define EPSV 1e-8f

typedef float f32x8 __attribute__((ext_vector_type(8)));

#define SMEM_FLOATS 36368
#define SMEM_BYTES  (SMEM_FLOATS * 4)

#define ROWS16(OP)                                                            \
  OP(0) OP(1) OP(2) OP(3) OP(4) OP(5) OP(6) OP(7)                             \
  OP(8) OP(9) OP(10) OP(11) OP(12) OP(13) OP(14) OP(15)

__device__ __forceinline__ float hsum8(f32x8 v) {
  return ((v.s0 + v.s1) + (v.s2 + v.s3)) + ((v.s4 + v.s5) + (v.s6 + v.s7));
}

__device__ __forceinline__ float wave_allred(float v) {
#pragma unroll
  for (int off = 32; off > 0; off >>= 1) v += __shfl_xor(v, off);
  return v;
}

#define FMA16(c, a, b)                                                        \
  c[0][0] += a.x * b.x; c[0][1] += a.x * b.y; c[0][2] += a.x * b.z; c[0][3] += a.x * b.w; \
  c[1][0] += a.y * b.x; c[1][1] += a.y * b.y; c[1][2] += a.y * b.z; c[1][3] += a.y * b.w; \
  c[2][0] += a.z * b.x; c[2][1] += a.z * b.y; c[2][2] += a.z * b.z; c[2][3] += a.z * b.w; \
  c[3][0] += a.w * b.x; c[3][1] += a.w * b.y; c[3][2] += a.w * b.z; c[3][3] += a.w * b.w;

// ---------------------------------------------------------------- k_gram ----
__global__ __launch_bounds__(256) void k_gram(const float* __restrict__ X,
                                              float* __restrict__ G) {
  const int bi = blockIdx.y, bj = blockIdx.x;
  if (bj > bi) return;
  __shared__ float Xa[32][68];
  __shared__ float Xb[32][68];
  const int tid = threadIdx.x;
  const int tx = tid & 15, ty = tid >> 4;
  float c[4][4] = {};
  for (int k0 = 0; k0 < 1024; k0 += 32) {
    __syncthreads();
    {
      const int row = tid >> 2, kk = (tid & 3) * 8;
      const float* pa = X + (bi * 64 + row) * 1024 + k0 + kk;
      const float4 a0 = *(const float4*)pa;
      const float4 a1 = *(const float4*)(pa + 4);
      Xa[kk + 0][row] = a0.x; Xa[kk + 1][row] = a0.y;
      Xa[kk + 2][row] = a0.z; Xa[kk + 3][row] = a0.w;
      Xa[kk + 4][row] = a1.x; Xa[kk + 5][row] = a1.y;
      Xa[kk + 6][row] = a1.z; Xa[kk + 7][row] = a1.w;
      const float* pb = X + (bj * 64 + row) * 1024 + k0 + kk;
      const float4 b0 = *(const float4*)pb;
      const float4 b1 = *(const float4*)(pb + 4);
      Xb[kk + 0][row] = b0.x; Xb[kk + 1][row] = b0.y;
      Xb[kk + 2][row] = b0.z; Xb[kk + 3][row] = b0.w;
      Xb[kk + 4][row] = b1.x; Xb[kk + 5][row] = b1.y;
      Xb[kk + 6][row] = b1.z; Xb[kk + 7][row] = b1.w;
    }
    __syncthreads();
#pragma unroll
    for (int kk = 0; kk < 32; kk++) {
      const float4 a = *(const float4*)&Xa[kk][ty * 4];
      const float4 b = *(const float4*)&Xb[kk][tx * 4];
      FMA16(c, a, b)
    }
  }
#pragma unroll
  for (int ii = 0; ii < 4; ii++) {
    *(float4*)(G + (bi * 64 + ty * 4 + ii) * 1024 + bj * 64 + tx * 4) =
        make_float4(c[ii][0], c[ii][1], c[ii][2], c[ii][3]);
  }
}

// ----------------------------------------------------------------- k_z10 ----
__global__ __launch_bounds__(256) void k_z10(const float* __restrict__ X,
                                             const float* __restrict__ W1g,
                                             float* __restrict__ Z10) {
  const int bi = blockIdx.y, bj = blockIdx.x;
  __shared__ float At[32][68];
  __shared__ float Bt[32][68];
  const int tid = threadIdx.x;
  const int tx = tid & 15, ty = tid >> 4;
  float c[4][4] = {};
  for (int k0 = 0; k0 < 1024; k0 += 32) {
    __syncthreads();
    {
      const int row = tid >> 2, kk = (tid & 3) * 8;
      const float* pa = X + (bi * 64 + row) * 1024 + k0 + kk;
      const float4 a0 = *(const float4*)pa;
      const float4 a1 = *(const float4*)(pa + 4);
      At[kk + 0][row] = a0.x; At[kk + 1][row] = a0.y;
      At[kk + 2][row] = a0.z; At[kk + 3][row] = a0.w;
      At[kk + 4][row] = a1.x; At[kk + 5][row] = a1.y;
      At[kk + 6][row] = a1.z; At[kk + 7][row] = a1.w;
      const int kr = tid >> 3, j8 = (tid & 7) * 8;
      const float* pb = W1g + (k0 + kr) * 256 + bj * 64 + j8;
      *(float4*)&Bt[kr][j8]     = *(const float4*)pb;
      *(float4*)&Bt[kr][j8 + 4] = *(const float4*)(pb + 4);
    }
    __syncthreads();
#pragma unroll
    for (int kk = 0; kk < 32; kk++) {
      const float4 a = *(const float4*)&At[kk][ty * 4];
      const float4 b = *(const float4*)&Bt[kk][tx * 4];
      FMA16(c, a, b)
    }
  }
#pragma unroll
  for (int ii = 0; ii < 4; ii++) {
    *(float4*)(Z10 + (bi * 64 + ty * 4 + ii) * 256 + bj * 64 + tx * 4) =
        make_float4(c[ii][0], c[ii][1], c[ii][2], c[ii][3]);
  }
}

// --------------------------------------------------------------- k_w1out ----
__global__ __launch_bounds__(256) void k_w1out(
    const float* __restrict__ X, const float* __restrict__ o1g,
    const float* __restrict__ cg, const float* __restrict__ W1g,
    const float* __restrict__ sclg, float* __restrict__ outW1) {
  const int bi = blockIdx.y, bj = blockIdx.x;
  __shared__ float At[32][68];
  __shared__ float Bt[32][68];
  const int tid = threadIdx.x;
  const int tx = tid & 15, ty = tid >> 4;
  float c[4][4] = {};
  for (int k0 = 0; k0 < 1024; k0 += 32) {
    __syncthreads();
    {
      const int kr = tid >> 3, m8 = (tid & 7) * 8;
      const float* pa = X + (k0 + kr) * 1024 + bi * 64 + m8;
      *(float4*)&At[kr][m8]     = *(const float4*)pa;
      *(float4*)&At[kr][m8 + 4] = *(const float4*)(pa + 4);
      const float cs = cg[k0 + kr];
      const float* pb = o1g + (k0 + kr) * 256 + bj * 64 + m8;
      float4 b0 = *(const float4*)pb;
      float4 b1 = *(const float4*)(pb + 4);
      b0.x *= cs; b0.y *= cs; b0.z *= cs; b0.w *= cs;
      b1.x *= cs; b1.y *= cs; b1.z *= cs; b1.w *= cs;
      *(float4*)&Bt[kr][m8]     = b0;
      *(float4*)&Bt[kr][m8 + 4] = b1;
    }
    __syncthreads();
#pragma unroll
    for (int kk = 0; kk < 32; kk++) {
      const float4 a = *(const float4*)&At[kk][ty * 4];
      const float4 b = *(const float4*)&Bt[kk][tx * 4];
      FMA16(c, a, b)
    }
  }
  const float s1f = sclg[0];
#pragma unroll
  for (int ii = 0; ii < 4; ii++) {
    const int row = bi * 64 + ty * 4 + ii;
    const float4 w = *(const float4*)(W1g + row * 256 + bj * 64 + tx * 4);
    *(float4*)(outW1 + row * 256 + bj * 64 + tx * 4) =
        make_float4(s1f * (w.x + c[ii][0]), s1f * (w.y + c[ii][1]),
                    s1f * (w.z + c[ii][2]), s1f * (w.w + c[ii][3]));
  }
}

// ---------------------------------------------------------------- k2_seq ----
__device__ __forceinline__ float block_reduce8(float v, float* tmp, int tid) {
#pragma unroll
  for (int off = 32; off > 0; off >>= 1) v += __shfl_xor(v, off);
  __syncthreads();
  if ((tid & 63) == 0) tmp[tid >> 6] = v;
  __syncthreads();
  float s = 0.f;
#pragma unroll
  for (int w = 0; w < 8; w++) s += tmp[w];
  __syncthreads();
  return s;
}

__global__ __launch_bounds__(512, 1) void k2_seq(
    const float* __restrict__ Tg, const float* __restrict__ W1g,
    const float* __restrict__ b1g, const float* __restrict__ W2g,
    const float* __restrict__ b2g, const float* __restrict__ W3g,
    const float* __restrict__ b3g, const float* __restrict__ G,
    const float* __restrict__ Z10, float* __restrict__ o1g,
    float* __restrict__ cg, float* __restrict__ sclg,
    float* __restrict__ outW2, float* __restrict__ outW3) {
  extern __shared__ float sm[];
  float* const zo   = sm;            // [64][272]: z1p row l until step l, then o1
  float* const Gb   = sm + 17408;    // [64][64] plain / [64][33] prefix staging
  float* const scr  = sm + 21504;    // 8448 floats: partials / o1 staging
  float* const Tb   = sm + 29952;    // [64][64] targets for this block
  float* const a1v  = sm + 34048;    // [2][256] double-buffered by step parity
  float* const z1v  = sm + 34560;    // 256
  float* const z2v  = sm + 34816;    // 256 (physical z2)
  float* const a2v  = sm + 35072;    // 256
  float* const o2v  = sm + 35328;    // 256 (physical o2)
  float* const b1ps = sm + 35584;    // 256 (pre-norm physical b1)
  float* const b2ps = sm + 35840;    // 256
  float* const d3v  = sm + 36096;    // 64
  float* const b3ps = sm + 36160;    // 64
  float* const ch   = sm + 36224;    // 64  in-block c coefficients
  float* const dpart= sm + 36288;    // 40  dot wave-partials
  float* const sca  = sm + 36328;    // 8   {s1, rb1, s2, rb2, s3, rb3, cw2, cw3}
  float* const cpre = sm + 36336;    // 32

  const int tid = threadIdx.x;
  const int p = tid >> 5;  // 0..15 : 16-row group
  const int q = tid & 31;  // 0..31 : 8-col group (W2) / 2-col group (W3)

  // ---- persistent per-thread state as named SSA values (no arrays!) ----
  // W2_phys = s2 * W2_i  (lazy scale) ; W3_phys = s3 * W3{x,y}_i
  f32x8 W2_0, W2_1, W2_2, W2_3, W2_4, W2_5, W2_6, W2_7,
        W2_8, W2_9, W2_10, W2_11, W2_12, W2_13, W2_14, W2_15;
  float W3x_0, W3x_1, W3x_2, W3x_3, W3x_4, W3x_5, W3x_6, W3x_7,
        W3x_8, W3x_9, W3x_10, W3x_11, W3x_12, W3x_13, W3x_14, W3x_15;
  float W3y_0, W3y_1, W3y_2, W3y_3, W3y_4, W3y_5, W3y_6, W3y_7,
        W3y_8, W3y_9, W3y_10, W3y_11, W3y_12, W3y_13, W3y_14, W3y_15;

#define INIT_ROW(i)                                                           \
  { const int row = p * 16 + i;                                               \
    W2_##i  = *(const f32x8*)(W2g + row * 256 + q * 8);                       \
    W3x_##i = W3g[row * 64 + q * 2];                                          \
    W3y_##i = W3g[row * 64 + q * 2 + 1]; }
  ROWS16(INIT_ROW)

  if (tid < 256) { b1ps[tid] = b1g[tid]; b2ps[tid] = b2g[tid]; }
  if (tid < 64) b3ps[tid] = b3g[tid];
  if (tid == 0) {
    sca[0] = 1.f; sca[1] = 1.f; sca[2] = 1.f; sca[3] = 1.f;
    sca[4] = 1.f; sca[5] = 1.f; sca[6] = 0.f; sca[7] = 0.f;
  }

  // Initial squared norms (broadcast to all threads; recurrence on wave 0).
  float acc1 = 0.f;
  for (int i = tid; i < 65536; i += 512) {
    const float4 v = ((const float4*)W1g)[i];
    acc1 += v.x * v.x + v.y * v.y + v.z * v.z + v.w * v.w;
  }
  const float n1init = block_reduce8(acc1, scr, tid);
  float acc2 = 0.f;
#define N2_ROW(i) { f32x8 t = W2_##i * W2_##i; acc2 += hsum8(t); }
  ROWS16(N2_ROW)
  const float n2init = block_reduce8(acc2, scr, tid);
  float acc3 = 0.f;
#define N3_ROW(i) acc3 += W3x_##i * W3x_##i + W3y_##i * W3y_##i;
  ROWS16(N3_ROW)
  const float n3init = block_reduce8(acc3, scr, tid);

  // Scalar recurrence state (meaningful on wave 0 only).
  float s1 = 1.f, s2 = 1.f, s3 = 1.f;
  double n1d = (double)n1init;
  float n2 = n2init, n3 = n3init;
  __syncthreads();

  for (int b = 0; b < 16; b++) {
    const int bs = b * 64;
    // ---- prefix: zo[row][j] = Z10[bs+row][j] + sum_{s<bs} cg[s]G[bs+row][s]o1[s][j]
    {
      f32x8 pacc0 = {0.f, 0.f, 0.f, 0.f, 0.f, 0.f, 0.f, 0.f};
      f32x8 pacc1 = pacc0, pacc2 = pacc0, pacc3 = pacc0;
      for (int c0 = 0; c0 < bs; c0 += 32) {
        __syncthreads();
        if (tid < 32) cpre[tid] = cg[c0 + tid];
        {
          const int row = tid >> 3, k4 = (tid & 7) * 4;
          const float4 gv = *(const float4*)(G + (bs + row) * 1024 + c0 + k4);
          Gb[row * 33 + k4 + 0] = gv.x; Gb[row * 33 + k4 + 1] = gv.y;
          Gb[row * 33 + k4 + 2] = gv.z; Gb[row * 33 + k4 + 3] = gv.w;
        }
#pragma unroll
        for (int u = 0; u < 4; u++) {
          const int fi = tid + u * 512;
          ((float4*)scr)[fi] = ((const float4*)(o1g + c0 * 256))[fi];
        }
        __syncthreads();
#pragma unroll 2
        for (int ss = 0; ss < 32; ss++) {
          const float cs = cpre[ss];
          const f32x8 o8 = *(const f32x8*)(scr + ss * 256 + q * 8);
          pacc0 += (Gb[(p * 4 + 0) * 33 + ss] * cs) * o8;
          pacc1 += (Gb[(p * 4 + 1) * 33 + ss] * cs) * o8;
          pacc2 += (Gb[(p * 4 + 2) * 33 + ss] * cs) * o8;
          pacc3 += (Gb[(p * 4 + 3) * 33 + ss] * cs) * o8;
        }
      }
      __syncthreads();
#define ZSTORE(rr)                                                            \
      { const int row = p * 4 + rr;                                           \
        *(f32x8*)(zo + row * 272 + q * 8) =                                   \
            *(const f32x8*)(Z10 + (bs + row) * 256 + q * 8) + pacc##rr; }
      ZSTORE(0) ZSTORE(1) ZSTORE(2) ZSTORE(3)
      // this block's 64x64 Gram square (plain layout) + targets
#pragma unroll
      for (int u = 0; u < 2; u++) {
        const int fi = tid + u * 512;
        const int row = fi >> 4, c4 = fi & 15;
        *(float4*)(Gb + row * 64 + c4 * 4) =
            *(const float4*)(G + (bs + row) * 1024 + bs + c4 * 4);
      }
      ((float4*)Tb)[tid]       = ((const float4*)(Tg + bs * 64))[tid];
      ((float4*)Tb)[tid + 512] = ((const float4*)(Tg + bs * 64))[tid + 512];
      __syncthreads();
    }

    // ---- 64 sequential steps, 10 barrier-fenced phases each
    for (int l = 0; l < 64; l++) {
      const int t = bs + l;
      const int cur = (t & 1) * 256, prv = 256 - cur;
      const float s1c = sca[0], rb1c = sca[1], s2c = sca[2],
                  rb2c = sca[3], s3c = sca[4], rb3c = sca[5];
      // Phase 1: deferred W2/W3 rank-1 update (prev step, pure-register)
      //          fused with A (z1 history + a1) — overlaps A's LDS latency.
      if (t > 0) {
        const float cw2 = sca[6], cw3 = sca[7];
        const f32x8 o8s = cw2 * (*(const f32x8*)&o2v[q * 8]);
        const float d0s = cw3 * d3v[q * 2], d1s = cw3 * d3v[q * 2 + 1];
#define UPD_ROW(i)                                                            \
        { const float a1o = a1v[prv + p * 16 + i];                            \
          W2_##i += a1o * o8s;                                                \
          const float a2o = a2v[p * 16 + i];                                  \
          W3x_##i += a2o * d0s; W3y_##i += a2o * d1s; }
        ROWS16(UPD_ROW)
      }
      {
        const int j = tid >> 1, half = tid & 1;
        float a = 0.f;
        for (int lp = half; lp < l; lp += 2)
          a += ch[lp] * Gb[l * 64 + lp] * zo[lp * 272 + j];
        a += __shfl_xor(a, 1);
        if (half == 0) {
          const float z1u = zo[l * 272 + j] + a;
          z1v[j] = z1u;
          const float z = s1c * z1u + rb1c * b1ps[j];
          a1v[cur + j] = 1.f / (1.f + expf(-z));
        }
      }
      __syncthreads();
      // Phase 2 (B1): z2 partials = a1 @ R2 (unscaled)
      {
        f32x8 acc = {0.f, 0.f, 0.f, 0.f, 0.f, 0.f, 0.f, 0.f};
#define B1_ROW(i) acc += a1v[cur + p * 16 + i] * W2_##i;
        ROWS16(B1_ROW)
        *(f32x8*)&scr[p * 264 + q * 8] = acc;
      }
      __syncthreads();
      // Phase 3 (B2): reduce, apply s2, sigmoid with folded rb2·b2p
      if (tid < 256) {
        float s = 0.f;
#pragma unroll
        for (int pp = 0; pp < 16; pp++) s += scr[pp * 264 + tid];
        const float z2p = s2c * s;
        z2v[tid] = z2p;
        a2v[tid] = 1.f / (1.f + expf(-(z2p + rb2c * b2ps[tid])));
      }
      __syncthreads();
      // Phase 4 (C1): z3 partials = a2 @ R3
      {
        float c0a = 0.f, c1a = 0.f;
#define C1_ROW(i)                                                             \
        { const float a2x = a2v[p * 16 + i];                                  \
          c0a += a2x * W3x_##i; c1a += a2x * W3y_##i; }
        ROWS16(C1_ROW)
        scr[(q * 2 + 0) * 17 + p] = c0a;
        scr[(q * 2 + 1) * 17 + p] = c1a;
      }
      __syncthreads();
      // Phase 5 (C2): z3, a3, softmax(-a3), d3, b3'; fused d3-dots
      if (tid < 64) {
        float s = 0.f;
#pragma unroll
        for (int pp = 0; pp < 16; pp++) s += scr[tid * 17 + pp];
        const float z3p = s3c * s;
        const float a3 = 1.f / (1.f + expf(-(z3p + rb3c * b3ps[tid])));
        const float e = expf(-a3);
        const float tot = wave_allred(e);
        const float outv = e / tot;
        const float d3 = (Tb[l * 64 + tid] - outv) * a3 * (1.f - a3);
        d3v[tid] = d3;
        const float b3n = rb3c * b3ps[tid] - LRC * d3;
        b3ps[tid] = b3n;
        const float v5 = wave_allred(z3p * d3);
        const float v7 = wave_allred(d3 * d3);
        const float v10 = wave_allred(b3n * b3n);
        if (tid == 0) { dpart[32] = v5; dpart[33] = v7; dpart[34] = v10; }
      }
      __syncthreads();
      // Phase 6 (E1): o2 partials = R3 @ d3
      {
        const float d0 = d3v[q * 2 + 0], d1 = d3v[q * 2 + 1];
#define E1_ROW(i) scr[(p * 16 + i) * 33 + q] = W3x_##i * d0 + W3y_##i * d1;
        ROWS16(E1_ROW)
      }
      __syncthreads();
      // Phase 7 (E2): reduce, apply s3, sigmoid-deriv, b2'; fused dots
      if (tid < 256) {
        float s = 0.f;
#pragma unroll
        for (int qq = 0; qq < 32; qq++) s += scr[tid * 33 + qq];
        const float a2x = a2v[tid];
        const float o2 = s3c * s * a2x * (1.f - a2x);
        o2v[tid] = o2;
        const float b2n = rb2c * b2ps[tid] - LRC * o2;
        b2ps[tid] = b2n;
        const float v2 = wave_allred(z2v[tid] * o2);
        const float v4 = wave_allred(o2 * o2);
        const float v6 = wave_allred(a2x * a2x);
        const float v9 = wave_allred(b2n * b2n);
        if ((tid & 63) == 0) {
          const int w = tid >> 6;
          dpart[16 + w] = v2; dpart[20 + w] = v4;
          dpart[24 + w] = v6; dpart[28 + w] = v9;
        }
      }
      __syncthreads();
      // Phase 8 (F1): o1 partials = R2 @ o2 (vector mul + horizontal sum)
      {
        const f32x8 ov8 = *(const f32x8*)&o2v[q * 8];
#define F1_ROW(i)                                                             \
        { f32x8 tmp = W2_##i * ov8; scr[(p * 16 + i) * 33 + q] = hsum8(tmp); }
        ROWS16(F1_ROW)
      }
      __syncthreads();
      // Phase 9 (F2): reduce, apply s2, o1 into zo (LDS only!), b1'; dots
      if (tid < 256) {
        float s = 0.f;
#pragma unroll
        for (int qq = 0; qq < 32; qq++) s += scr[tid * 33 + qq];
        const float a1x = a1v[cur + tid];
        const float o1x = s2c * s * a1x * (1.f - a1x);
        zo[l * 272 + tid] = o1x;          // overwrite z1p row l with o1
        const float b1n = rb1c * b1ps[tid] - LRC * o1x;
        b1ps[tid] = b1n;
        const float v0 = wave_allred(z1v[tid] * o1x);
        const float v1 = wave_allred(o1x * o1x);
        const float v3 = wave_allred(a1x * a1x);
        const float v8 = wave_allred(b1n * b1n);
        if ((tid & 63) == 0) {
          const int w = tid >> 6;
          dpart[0 + w] = v0; dpart[4 + w] = v1;
          dpart[8 + w] = v3; dpart[12 + w] = v8;
        }
      }
      __syncthreads();
      // Phase 10 (Hs): scalar norm recurrences on wave 0 only; broadcast.
      if (tid < 64) {
        const float dts0 = (dpart[0] + dpart[1]) + (dpart[2] + dpart[3]);
        const float dts1 = (dpart[4] + dpart[5]) + (dpart[6] + dpart[7]);
        const float dts3 = (dpart[8] + dpart[9]) + (dpart[10] + dpart[11]);
        const float dts8 = (dpart[12] + dpart[13]) + (dpart[14] + dpart[15]);
        const float dts2 = (dpart[16] + dpart[17]) + (dpart[18] + dpart[19]);
        const float dts4 = (dpart[20] + dpart[21]) + (dpart[22] + dpart[23]);
        const float dts6 = (dpart[24] + dpart[25]) + (dpart[26] + dpart[27]);
        const float dts9 = (dpart[28] + dpart[29]) + (dpart[30] + dpart[31]);
        const float dts5 = dpart[32], dts7 = dpart[33], dts10 = dpart[34];
        const float c1 = -LRC / s1;
        const double gtt = (double)Gb[l * 64 + l];
        n1d = n1d + 2.0 * (double)c1 * (double)dts0 +
              (double)c1 * (double)c1 * gtt * (double)dts1;
        const double w1n = (double)s1 * sqrt(n1d);
        s1 = (float)((double)s1 / fmax(w1n, (double)EPSV));
        const float n2p = n2 - 2.f * LRC * dts2 + LRC * LRC * dts3 * dts4;
        const float r2s = 1.f / fmaxf(sqrtf(n2p), EPSV);
        n2 = n2p * r2s * r2s;
        const float cw2 = -LRC / s2;
        s2 = s2 * r2s;
        const float n3p = n3 - 2.f * LRC * dts5 + LRC * LRC * dts6 * dts7;
        const float r3s = 1.f / fmaxf(sqrtf(n3p), EPSV);
        n3 = n3p * r3s * r3s;
        const float cw3 = -LRC / s3;
        s3 = s3 * r3s;
        if (tid == 0) {
          ch[l] = c1;
          sca[0] = s1;
          sca[1] = 1.f / fmaxf(sqrtf(dts8), EPSV);
          sca[2] = s2;
          sca[3] = 1.f / fmaxf(sqrtf(dts9), EPSV);
          sca[4] = s3;
          sca[5] = 1.f / fmaxf(sqrtf(dts10), EPSV);
          sca[6] = cw2;
          sca[7] = cw3;
        }
      }
      __syncthreads();
    }

    // ---- per-block flush of o1 (from zo) and c (from ch) to global
    {
#pragma unroll
      for (int u = 0; u < 4; u++) {
        const int chunk = tid + u * 512;          // 0..2047
        const int row = chunk >> 5, c8 = chunk & 31;
        *(f32x8*)(o1g + (bs + row) * 256 + c8 * 8) =
            *(const f32x8*)(zo + row * 272 + c8 * 8);
      }
      if (tid < 64) cg[bs + tid] = ch[tid];
    }
    // next block's prefix __syncthreads() drains these stores before reads
  }

  // ---- epilogue: apply deferred update of step 1023, write scaled outputs
  {
    const float cw2 = sca[6], cw3 = sca[7];
    const float s2f = sca[2], s3f = sca[4];
    const f32x8 o8s = cw2 * (*(const f32x8*)&o2v[q * 8]);
    const float d0s = cw3 * d3v[q * 2], d1s = cw3 * d3v[q * 2 + 1];
#define FIN_ROW(i)                                                            \
    { const float a1o = a1v[256 + p * 16 + i]; /* parity of t=1023 */         \
      W2_##i += a1o * o8s;                                                    \
      const float a2o = a2v[p * 16 + i];                                      \
      W3x_##i += a2o * d0s; W3y_##i += a2o * d1s;                             \
      const int row = p * 16 + i;                                             \
      *(f32x8*)(outW2 + row * 256 + q * 8) = s2f * W2_##i;                    \
      outW3[row * 64 + q * 2]     = s3f * W3x_##i;                            \
      outW3[row * 64 + q * 2 + 1] = s3f * W3y_##i; }
    ROWS16(FIN_ROW)
    if (tid == 0) sclg[0] = sca[0];
  }
}

// ---------------------------------------------------------------- launch ----
extern "C" void kernel_launch(void* const* d_in, const int* in_sizes, int n_in,
                              void* d_out, int out_size, void* d_ws,
                              size_t ws_size, hipStream_t stream) {
  (void)in_sizes; (void)n_in; (void)out_size; (void)ws_size;
  const float* X   = (const float*)d_in[0];
  const float* Tg  = (const float*)d_in[1];
  const float* W1g = (const float*)d_in[2];
  const float* b1g = (const float*)d_in[3];
  const float* W2g = (const float*)d_in[4];
  const float* b2g = (const float*)d_in[5];
  const float* W3g = (const float*)d_in[6];
  const float* b3g = (const float*)d_in[7];
  float* out = (float*)d_out;
  float* ws  = (float*)d_ws;

  float* G    = ws;
  float* Z10  = G + 1048576;
  float* o1g  = Z10 + 262144;
  float* cg   = o1g + 262144;
  float* sclg = cg + 1024;

  (void)hipFuncSetAttribute((const void*)k2_seq,
                            hipFuncAttributeMaxDynamicSharedMemorySize,
                            SMEM_BYTES);

  k_gram<<<dim3(16, 16), 256, 0, stream>>>(X, G);
  k_z10<<<dim3(4, 16), 256, 0, stream>>>(X, W1g, Z10);
  k2_seq<<<dim3(1), dim3(512), SMEM_BYTES, stream>>>(
      Tg, W1g, b1g, W2g, b2g, W3g, b3g, G, Z10, o1g, cg, sclg,
      out + 262144, out + 327680);
  k_w1out<<<dim3(4, 16), 256, 0, stream>>>(X, o1g, cg, W1g, sclg, out);
}